// Round 6
// baseline (111.850 us; speedup 1.0000x reference)
//
#include <hip/hip_runtime.h>
#include <hip/hip_cooperative_groups.h>
#include <math.h>

namespace cg = cooperative_groups;

#define BATCH   64
#define NFEAT   256
#define GS      4
#define NG      64
#define WH      3136            // 56*56
#define PLANEQ  784             // WH/4 (float4 quads per channel plane)
#define NTOT    (BATCH*WH)      // 200704 samples per channel
#define EPSV    1e-3
#define PREC    16              // padded floats per partial record
#define COOP_GRID 2048          // 2 (b,g)-tiles per block

typedef float vf4 __attribute__((ext_vector_type(4)));

// ===================== Jacobi helper (lane-serial) =====================
// From double sums acc[14] (4 means-sums + 10 products) produce
// wo[0..15]=W, wo[16..19]=-W m, wo[20..23]=m.
__device__ void solve_group(const double* acc, float* wo) {
    const double n = (double)NTOT;
    double m[4];
    #pragma unroll
    for (int i = 0; i < 4; ++i) m[i] = acc[i] / n;

    const int pi[10] = {0,0,0,0,1,1,1,2,2,3};
    const int pj[10] = {0,1,2,3,1,2,3,2,3,3};

    double A[4][4];
    #pragma unroll
    for (int t = 0; t < 10; ++t) {
        double cov = acc[4 + t] - n * m[pi[t]] * m[pj[t]];
        double v = (1.0 - EPSV) * cov + ((pi[t] == pj[t]) ? EPSV : 0.0);
        A[pi[t]][pj[t]] = v;
        A[pj[t]][pi[t]] = v;
    }

    double V[4][4] = {{1,0,0,0},{0,1,0,0},{0,0,1,0},{0,0,0,1}};
    const double tr = A[0][0] + A[1][1] + A[2][2] + A[3][3];
    const double tol = 1e-26 * tr * tr + 1e-300;
    const int rp[6] = {0,0,0,1,1,2};
    const int rq[6] = {1,2,3,2,3,3};

    for (int sweep = 0; sweep < 10; ++sweep) {
        double off = 0.0;
        #pragma unroll
        for (int t = 0; t < 6; ++t) off += A[rp[t]][rq[t]] * A[rp[t]][rq[t]];
        if (off < tol) break;
        #pragma unroll
        for (int t = 0; t < 6; ++t) {
            const int p = rp[t], q = rq[t];
            double apq = A[p][q];
            if (apq * apq < 1e-60) continue;
            double theta = (A[q][q] - A[p][p]) / (2.0 * apq);
            double tt = ((theta >= 0.0) ? 1.0 : -1.0) /
                        (fabs(theta) + sqrt(theta * theta + 1.0));
            double c = 1.0 / sqrt(tt * tt + 1.0);
            double s = tt * c;
            #pragma unroll
            for (int k = 0; k < 4; ++k) {
                double akp = A[k][p], akq = A[k][q];
                A[k][p] = c * akp - s * akq;
                A[k][q] = s * akp + c * akq;
            }
            #pragma unroll
            for (int k = 0; k < 4; ++k) {
                double apk = A[p][k], aqk = A[q][k];
                A[p][k] = c * apk - s * aqk;
                A[q][k] = s * apk + c * aqk;
            }
            #pragma unroll
            for (int k = 0; k < 4; ++k) {
                double vkp = V[k][p], vkq = V[k][q];
                V[k][p] = c * vkp - s * vkq;
                V[k][q] = s * vkp + c * vkq;
            }
        }
    }

    double isq[4];
    #pragma unroll
    for (int k = 0; k < 4; ++k) isq[k] = 1.0 / sqrt(A[k][k] + EPSV);

    double Wd[4][4];
    #pragma unroll
    for (int i = 0; i < 4; ++i) {
        #pragma unroll
        for (int j = 0; j < 4; ++j) {
            double w = 0.0;
            #pragma unroll
            for (int k = 0; k < 4; ++k) w += V[i][k] * V[j][k] * isq[k];
            Wd[i][j] = w;
            wo[i * 4 + j] = (float)w;
        }
    }
    #pragma unroll
    for (int i = 0; i < 4; ++i) {
        double wmI = Wd[i][0]*m[0] + Wd[i][1]*m[1] + Wd[i][2]*m[2] + Wd[i][3]*m[3];
        wo[16 + i] = (float)(-wmI);
        wo[20 + i] = (float)m[i];
    }
}

// ===================== Fused cooperative kernel =====================
// 2048 blocks x 256 thr, all co-resident. Block B owns batch b=B>>5 and
// groups g0=2*(B&31), g0+1. x is loaded ONCE into registers (2x16 vf4),
// reduced, grid-synced, 64 blocks eigen-solve, grid-synced, applied.
__global__ __launch_bounds__(256, 8) void wh_fused(const float* __restrict__ x,
                                                   float* __restrict__ partials,
                                                   float* __restrict__ wm,
                                                   float* __restrict__ out) {
    cg::grid_group grid = cg::this_grid();
    const int B   = blockIdx.x;
    const int tid = threadIdx.x;
    const int b   = B >> 5;
    const int g0  = (B & 31) << 1;

    const size_t base0 = (size_t)b * ((size_t)NFEAT * WH) + (size_t)g0 * (GS * WH);
    const vf4* __restrict__ x0 = (const vf4*)(x + base0);
    const vf4* __restrict__ x1 = x0 + GS * PLANEQ;

    const bool tail = (tid < PLANEQ - 3 * 256);    // 16 tail quads
    const int  qt   = 768 + (tid & 15);            // always in-bounds

    // ---- Phase 1a: load both tiles into registers ----
    vf4 d0[16], d1[16];   // [c*4 + r], r=0..2 strided, r=3 tail
    #pragma unroll
    for (int c = 0; c < 4; ++c) {
        #pragma unroll
        for (int r = 0; r < 3; ++r) {
            d0[c*4+r] = x0[c*PLANEQ + tid + 256*r];
            d1[c*4+r] = x1[c*PLANEQ + tid + 256*r];
        }
    }
    #pragma unroll
    for (int c = 0; c < 4; ++c) {
        vf4 t0 = x0[c*PLANEQ + qt];
        vf4 t1 = x1[c*PLANEQ + qt];
        if (!tail) { t0 = (vf4){0.f,0.f,0.f,0.f}; t1 = (vf4){0.f,0.f,0.f,0.f}; }
        d0[c*4+3] = t0;
        d1[c*4+3] = t1;
    }

    // ---- Phase 1b: per-thread partial sums (zeros in tail lanes are exact) ----
    float vv[28];
    #pragma unroll
    for (int q = 0; q < 28; ++q) vv[q] = 0.f;

#define REDUCE_TILE(D, OFF)                                              \
    {                                                                    \
        _Pragma("unroll")                                                \
        for (int r = 0; r < 4; ++r) {                                    \
            _Pragma("unroll")                                            \
            for (int k = 0; k < 4; ++k) {                                \
                float A = D[0*4+r][k], Bv = D[1*4+r][k];                 \
                float C = D[2*4+r][k], Dv = D[3*4+r][k];                 \
                vv[OFF+0] += A; vv[OFF+1] += Bv;                         \
                vv[OFF+2] += C; vv[OFF+3] += Dv;                         \
                vv[OFF+4]  = fmaf(A,  A,  vv[OFF+4]);                    \
                vv[OFF+5]  = fmaf(A,  Bv, vv[OFF+5]);                    \
                vv[OFF+6]  = fmaf(A,  C,  vv[OFF+6]);                    \
                vv[OFF+7]  = fmaf(A,  Dv, vv[OFF+7]);                    \
                vv[OFF+8]  = fmaf(Bv, Bv, vv[OFF+8]);                    \
                vv[OFF+9]  = fmaf(Bv, C,  vv[OFF+9]);                    \
                vv[OFF+10] = fmaf(Bv, Dv, vv[OFF+10]);                   \
                vv[OFF+11] = fmaf(C,  C,  vv[OFF+11]);                   \
                vv[OFF+12] = fmaf(C,  Dv, vv[OFF+12]);                   \
                vv[OFF+13] = fmaf(Dv, Dv, vv[OFF+13]);                   \
            }                                                            \
        }                                                                \
    }
    REDUCE_TILE(d0, 0);
    REDUCE_TILE(d1, 14);
#undef REDUCE_TILE

    #pragma unroll
    for (int q = 0; q < 28; ++q) {
        float v = vv[q];
        #pragma unroll
        for (int off = 32; off > 0; off >>= 1) v += __shfl_down(v, off, 64);
        vv[q] = v;
    }

    __shared__ float lds[4][28];
    const int wave = tid >> 6;
    const int lane = tid & 63;
    if (lane == 0) {
        #pragma unroll
        for (int q = 0; q < 28; ++q) lds[wave][q] = vv[q];
    }
    __syncthreads();
    if (tid < 28) {
        float v = lds[0][tid] + lds[1][tid] + lds[2][tid] + lds[3][tid];
        const int s = tid / 14, q = tid - s * 14;
        partials[((size_t)((g0 + s) * BATCH + b)) * PREC + q] = v;
    }

    grid.sync();

    // ---- Phase 2: 64 blocks solve one group each ----
    if (B < NG && tid < 64) {
        const float* bse = partials + ((size_t)(B * BATCH + tid)) * PREC;
        double acc[14];
        #pragma unroll
        for (int q = 0; q < 14; ++q) acc[q] = (double)bse[q];
        #pragma unroll
        for (int off = 32; off > 0; off >>= 1) {
            #pragma unroll
            for (int q = 0; q < 14; ++q) acc[q] += __shfl_xor(acc[q], off, 64);
        }
        if (tid == 0) solve_group(acc, wm + B * 24);
    }

    grid.sync();

    // ---- Phase 3: apply from registers, NT-store out ----
    __shared__ float sW[40];
    if (tid < 20)                      sW[tid]        = wm[g0 * 24 + tid];
    else if (tid >= 32 && tid < 52)    sW[tid - 12]   = wm[(g0 + 1) * 24 + (tid - 32)];
    __syncthreads();

    float W0[4][4], n0[4], W1[4][4], n1[4];
    #pragma unroll
    for (int i = 0; i < 4; ++i) {
        #pragma unroll
        for (int j = 0; j < 4; ++j) { W0[i][j] = sW[i*4+j]; W1[i][j] = sW[20+i*4+j]; }
        n0[i] = sW[16 + i];
        n1[i] = sW[36 + i];
    }

    vf4* __restrict__ o0 = (vf4*)(out + base0);
    vf4* __restrict__ o1 = o0 + GS * PLANEQ;

#define APPLY_TILE(D, W, NW, O)                                          \
    {                                                                    \
        _Pragma("unroll")                                                \
        for (int i = 0; i < 4; ++i) {                                    \
            _Pragma("unroll")                                            \
            for (int r = 0; r < 3; ++r) {                                \
                vf4 rr;                                                  \
                _Pragma("unroll")                                        \
                for (int k = 0; k < 4; ++k) {                            \
                    rr[k] = fmaf(W[i][0], D[0*4+r][k],                   \
                            fmaf(W[i][1], D[1*4+r][k],                   \
                            fmaf(W[i][2], D[2*4+r][k],                   \
                            fmaf(W[i][3], D[3*4+r][k], NW[i]))));        \
                }                                                        \
                __builtin_nontemporal_store(rr, &O[i*PLANEQ + tid + 256*r]); \
            }                                                            \
            if (tail) {                                                  \
                vf4 rr;                                                  \
                _Pragma("unroll")                                        \
                for (int k = 0; k < 4; ++k) {                            \
                    rr[k] = fmaf(W[i][0], D[0*4+3][k],                   \
                            fmaf(W[i][1], D[1*4+3][k],                   \
                            fmaf(W[i][2], D[2*4+3][k],                   \
                            fmaf(W[i][3], D[3*4+3][k], NW[i]))));        \
                }                                                        \
                __builtin_nontemporal_store(rr, &O[i*PLANEQ + qt]);      \
            }                                                            \
        }                                                                \
    }
    APPLY_TILE(d0, W0, n0, o0);
    APPLY_TILE(d1, W1, n1, o1);
#undef APPLY_TILE
}

// ===================== Fallback 3-kernel path (R5) =====================
__global__ __launch_bounds__(256) void wh_reduce(const float* __restrict__ x,
                                                 float* __restrict__ partials) {
    const int blk = blockIdx.x;
    const int b = blk >> 6;
    const int g = blk & 63;
    const int tid = threadIdx.x;
    const vf4* __restrict__ xin =
        (const vf4*)(x + (size_t)b * ((size_t)NFEAT * WH) + (size_t)g * (GS * WH));

    float s0=0.f,s1=0.f,s2=0.f,s3=0.f;
    float p0=0.f,p1=0.f,p2=0.f,p3=0.f,p4=0.f,p5=0.f,p6=0.f,p7=0.f,p8=0.f,p9=0.f;

    for (int q = tid; q < PLANEQ; q += 256) {
        vf4 v0 = xin[q];
        vf4 v1 = xin[q + PLANEQ];
        vf4 v2 = xin[q + 2*PLANEQ];
        vf4 v3 = xin[q + 3*PLANEQ];
        #pragma unroll
        for (int k = 0; k < 4; ++k) {
            float A = v0[k], Bv = v1[k], C = v2[k], D = v3[k];
            s0 += A; s1 += Bv; s2 += C; s3 += D;
            p0 = fmaf(A, A, p0);   p1 = fmaf(A, Bv, p1);
            p2 = fmaf(A, C, p2);   p3 = fmaf(A, D, p3);
            p4 = fmaf(Bv, Bv, p4); p5 = fmaf(Bv, C, p5);
            p6 = fmaf(Bv, D, p6);  p7 = fmaf(C, C, p7);
            p8 = fmaf(C, D, p8);   p9 = fmaf(D, D, p9);
        }
    }

    float vals[14] = {s0,s1,s2,s3,p0,p1,p2,p3,p4,p5,p6,p7,p8,p9};
    #pragma unroll
    for (int q = 0; q < 14; ++q) {
        float v = vals[q];
        #pragma unroll
        for (int off = 32; off > 0; off >>= 1) v += __shfl_down(v, off, 64);
        vals[q] = v;
    }

    __shared__ float lds2[4][14];
    const int wave = tid >> 6;
    const int lane = tid & 63;
    if (lane == 0) {
        #pragma unroll
        for (int q = 0; q < 14; ++q) lds2[wave][q] = vals[q];
    }
    __syncthreads();
    if (tid < 14) {
        float v = lds2[0][tid] + lds2[1][tid] + lds2[2][tid] + lds2[3][tid];
        partials[((size_t)(g * BATCH + b)) * PREC + tid] = v;
    }
}

__global__ __launch_bounds__(64) void wh_eigen(const float* __restrict__ partials,
                                               float* __restrict__ wm) {
    const int g = blockIdx.x;
    const int b = threadIdx.x;
    const float* base = partials + ((size_t)(g * BATCH + b)) * PREC;
    double acc[14];
    #pragma unroll
    for (int q = 0; q < 14; ++q) acc[q] = (double)base[q];
    #pragma unroll
    for (int off = 32; off > 0; off >>= 1) {
        #pragma unroll
        for (int q = 0; q < 14; ++q) acc[q] += __shfl_xor(acc[q], off, 64);
    }
    if (b != 0) return;
    solve_group(acc, wm + g * 24);
}

__global__ __launch_bounds__(256) void wh_apply(const float* __restrict__ x,
                                                const float* __restrict__ wm,
                                                float* __restrict__ out) {
    const int blk = blockIdx.x;
    const int b = blk >> 6;
    const int g = blk & 63;
    const int tid = threadIdx.x;

    __shared__ float sW[20];
    if (tid < 20) sW[tid] = wm[g * 24 + tid];
    __syncthreads();

    float W[4][4], nwm[4];
    #pragma unroll
    for (int i = 0; i < 4; ++i) {
        #pragma unroll
        for (int j = 0; j < 4; ++j) W[i][j] = sW[i * 4 + j];
        nwm[i] = sW[16 + i];
    }

    const size_t off = (size_t)b * ((size_t)NFEAT * WH) + (size_t)g * (GS * WH);
    const vf4* __restrict__ xin = (const vf4*)(x + off);
    vf4* __restrict__ o = (vf4*)(out + off);

    for (int q = tid; q < PLANEQ; q += 256) {
        vf4 v0 = xin[q];
        vf4 v1 = xin[q + PLANEQ];
        vf4 v2 = xin[q + 2 * PLANEQ];
        vf4 v3 = xin[q + 3 * PLANEQ];
        #pragma unroll
        for (int i = 0; i < 4; ++i) {
            vf4 r;
            #pragma unroll
            for (int k = 0; k < 4; ++k) {
                r[k] = fmaf(W[i][0], v0[k],
                       fmaf(W[i][1], v1[k],
                       fmaf(W[i][2], v2[k],
                       fmaf(W[i][3], v3[k], nwm[i]))));
            }
            __builtin_nontemporal_store(r, &o[q + i * PLANEQ]);
        }
    }
}

extern "C" void kernel_launch(void* const* d_in, const int* in_sizes, int n_in,
                              void* d_out, int out_size, void* d_ws, size_t ws_size,
                              hipStream_t stream) {
    const float* x = (const float*)d_in[0];
    float* out = (float*)d_out;

    float* partials = (float*)d_ws;                          // 64*64*16 f = 256 KiB
    float* wm       = partials + (size_t)NG * BATCH * PREC;  // 64*24 f

    // Co-residency check (pure host queries; capture-safe, deterministic).
    int maxBlk = 0, numCU = 0;
    hipOccupancyMaxActiveBlocksPerMultiprocessor(&maxBlk, (const void*)wh_fused, 256, 0);
    hipDeviceGetAttribute(&numCU, hipDeviceAttributeMultiprocessorCount, 0);

    bool coop_ok = (maxBlk * numCU >= COOP_GRID);
    if (coop_ok) {
        void* args[4] = {(void*)&x, (void*)&partials, (void*)&wm, (void*)&out};
        hipError_t e = hipLaunchCooperativeKernel((const void*)wh_fused,
                                                  dim3(COOP_GRID), dim3(256),
                                                  args, 0, stream);
        if (e == hipSuccess) return;
    }

    // Fallback: proven 110 µs 3-kernel path.
    wh_reduce<<<BATCH * NG, 256, 0, stream>>>(x, partials);
    wh_eigen<<<NG, 64, 0, stream>>>(partials, wm);
    wh_apply<<<BATCH * NG, 256, 0, stream>>>(x, wm, out);
}